// Round 5
// baseline (1874.024 us; speedup 1.0000x reference)
//
#include <hip/hip_runtime.h>
#include <cstdint>
#include <cstddef>

#define VN 100000
#define EN 1600000
static constexpr float BN_EPS_F = 1e-5f;
static constexpr float INV_N = 1.0f / 400000.0f;   // B*V = 4*100000

using short8 = __attribute__((ext_vector_type(8))) short;
using f32x4  = __attribute__((ext_vector_type(4))) float;
using u32x2  = __attribute__((ext_vector_type(2))) unsigned int;

// ---------- bf16 helpers (manual, RTNE) ----------
__device__ __forceinline__ float bf_lo(unsigned int p) {
  return __builtin_bit_cast(float, p << 16);
}
__device__ __forceinline__ float bf_hi(unsigned int p) {
  return __builtin_bit_cast(float, p & 0xffff0000u);
}
__device__ __forceinline__ float bf1(unsigned short u) {
  return __builtin_bit_cast(float, ((unsigned int)u) << 16);
}
__device__ __forceinline__ unsigned short f2bf(float f) {
  unsigned int x = __builtin_bit_cast(unsigned int, f);
  x += 0x7fffu + ((x >> 16) & 1u);
  return (unsigned short)(x >> 16);
}
__device__ __forceinline__ unsigned int pack2(float a, float b) {
  return (unsigned int)f2bf(a) | ((unsigned int)f2bf(b) << 16);
}

// ---------- non-temporal (stream) loads: single-use data, don't pollute L2/L3 ----------
__device__ __forceinline__ unsigned int ntl_u32(const unsigned short* p) {
  return __builtin_nontemporal_load(reinterpret_cast<const unsigned int*>(p));
}
__device__ __forceinline__ u32x2 ntl_u32x2(const unsigned short* p) {
  return __builtin_nontemporal_load(reinterpret_cast<const u32x2*>(p));
}
__device__ __forceinline__ short8 ntl_s8(const unsigned short* p) {
  return __builtin_nontemporal_load(reinterpret_cast<const short8*>(p));
}

// ---------- CSR row gather+accumulate, 8/4/1-edge unroll (clean inner loop) ----------
template <int EPL>
__device__ __forceinline__ void gather_accum(int start, int end,
    const int* __restrict__ cs, const float* __restrict__ vs,
    const unsigned short* __restrict__ X, int XS, int lane, float* acc) {
  int e = start;
  if constexpr (EPL == 4) {
    for (; e + 8 <= end; e += 8) {
      uint2 q[8]; float w[8];
#pragma unroll
      for (int u = 0; u < 8; u++) {
        q[u] = *reinterpret_cast<const uint2*>(X + (size_t)cs[e + u] * XS + lane * 4);
        w[u] = vs[e + u];
      }
#pragma unroll
      for (int u = 0; u < 8; u++) {
        acc[0] += w[u] * bf_lo(q[u].x);
        acc[1] += w[u] * bf_hi(q[u].x);
        acc[2] += w[u] * bf_lo(q[u].y);
        acc[3] += w[u] * bf_hi(q[u].y);
      }
    }
    for (; e + 4 <= end; e += 4) {
      uint2 q[4]; float w[4];
#pragma unroll
      for (int u = 0; u < 4; u++) {
        q[u] = *reinterpret_cast<const uint2*>(X + (size_t)cs[e + u] * XS + lane * 4);
        w[u] = vs[e + u];
      }
#pragma unroll
      for (int u = 0; u < 4; u++) {
        acc[0] += w[u] * bf_lo(q[u].x);
        acc[1] += w[u] * bf_hi(q[u].x);
        acc[2] += w[u] * bf_lo(q[u].y);
        acc[3] += w[u] * bf_hi(q[u].y);
      }
    }
    for (; e < end; e++) {
      const uint2 q = *reinterpret_cast<const uint2*>(X + (size_t)cs[e] * XS + lane * 4);
      const float w = vs[e];
      acc[0] += w * bf_lo(q.x);
      acc[1] += w * bf_hi(q.x);
      acc[2] += w * bf_lo(q.y);
      acc[3] += w * bf_hi(q.y);
    }
  } else {
    for (; e + 8 <= end; e += 8) {
      unsigned int q[8]; float w[8];
#pragma unroll
      for (int u = 0; u < 8; u++) {
        q[u] = *reinterpret_cast<const unsigned int*>(X + (size_t)cs[e + u] * XS + lane * 2);
        w[u] = vs[e + u];
      }
#pragma unroll
      for (int u = 0; u < 8; u++) {
        acc[0] += w[u] * bf_lo(q[u]);
        acc[1] += w[u] * bf_hi(q[u]);
      }
    }
    for (; e + 4 <= end; e += 4) {
      unsigned int q[4]; float w[4];
#pragma unroll
      for (int u = 0; u < 4; u++) {
        q[u] = *reinterpret_cast<const unsigned int*>(X + (size_t)cs[e + u] * XS + lane * 2);
        w[u] = vs[e + u];
      }
#pragma unroll
      for (int u = 0; u < 4; u++) {
        acc[0] += w[u] * bf_lo(q[u]);
        acc[1] += w[u] * bf_hi(q[u]);
      }
    }
    for (; e < end; e++) {
      const unsigned int q = *reinterpret_cast<const unsigned int*>(X + (size_t)cs[e] * XS + lane * 2);
      const float w = vs[e];
      acc[0] += w * bf_lo(q);
      acc[1] += w * bf_hi(q);
    }
  }
}

// ---------- K1: per-channel sum/sumsq of input x (B,32,V) fp32 ----------
__global__ __launch_bounds__(256) void stats_x_kernel(const float* __restrict__ x,
                                                      float* __restrict__ stats) {
  const int p = blockIdx.x & 127;      // plane = (b,c)
  const int chunk = blockIdx.x >> 7;   // 0..7
  const int c = p & 31, b = p >> 5;
  const float* base = x + ((size_t)b * 32 + c) * VN + chunk * 12500;
  float s = 0.f, s2 = 0.f;
  for (int i = threadIdx.x; i < 12500; i += 256) {
    float v = base[i];
    s += v; s2 += v * v;
  }
  __shared__ float r1[256], r2[256];
  r1[threadIdx.x] = s; r2[threadIdx.x] = s2;
  __syncthreads();
  for (int off = 128; off > 0; off >>= 1) {
    if (threadIdx.x < off) {
      r1[threadIdx.x] += r1[threadIdx.x + off];
      r2[threadIdx.x] += r2[threadIdx.x + off];
    }
    __syncthreads();
  }
  if (threadIdx.x == 0) {
    atomicAdd(&stats[c], r1[0]);
    atomicAdd(&stats[64 + c], r2[0]);
  }
}

__global__ void finalize_stats_kernel(float* __restrict__ stats,
                                      const float* __restrict__ g,
                                      const float* __restrict__ beta, int C) {
  int c = threadIdx.x;
  if (c < C) {
    float m = stats[c] * INV_N;
    float var = stats[64 + c] * INV_N - m * m;
    float sc = g[c] * rsqrtf(var + BN_EPS_F);
    stats[128 + c] = sc;
    stats[192 + c] = beta[c] - m * sc;
  }
}

// ---------- K2: normalize input + transpose (B,32,V)->(V, B=4, C=32) bf16, stride 128 ----------
__global__ __launch_bounds__(128) void bn_transpose_kernel(const float* __restrict__ x,
                                                           const float* __restrict__ stats,
                                                           unsigned short* __restrict__ xn) {
  const int tid = threadIdx.x;       // tid = b*32 + c
  const int b = tid >> 5, c = tid & 31;
  const int v0 = blockIdx.x * 64;
  const float sc = stats[128 + c], sh = stats[192 + c];
  const float* src = x + ((size_t)b * 32 + c) * VN;
  for (int i = 0; i < 64; i++) {
    int v = v0 + i;
    if (v < VN) xn[(size_t)v * 128 + tid] = f2bf(sc * src[v] + sh);
  }
}

// ---------- W pre-pack: fp32 (K,Cin,Cout) -> bf16 MFMA B-fragment order ----------
// scale != nullptr: fold per-channel scale[c] into W[k][c][o] for k with (kmask>>k)&1
__global__ __launch_bounds__(256) void pack_wb_kernel(const float* __restrict__ W,
                                                      unsigned short* __restrict__ Wb,
                                                      int Cin, int Cout,
                                                      const float* __restrict__ scale,
                                                      int kmask) {
  const int i = blockIdx.x * 256 + threadIdx.x;
  const int KC = Cin >> 5, T = Cout >> 4;
  const int tot = 4 * KC * T * 512;
  if (i >= tot) return;
  const int j = i & 7;
  const int l = (i >> 3) & 63;
  const int rem = i >> 9;
  const int t = rem % T;
  const int kc = (rem / T) % KC;
  const int k = rem / (T * KC);
  const int c = kc * 32 + (l >> 4) * 8 + j;
  const int o = t * 16 + (l & 15);
  float w = W[((size_t)k * Cin + c) * Cout + o];
  if (scale != nullptr && ((kmask >> k) & 1)) w *= scale[c];
  Wb[i] = f2bf(w);
}

// ---------- bias fold: out[k*Cout+o] = (k==0 ? b0[o] : 0) + sum_c sh[c]*W[k][c][o] ----------
__global__ void bias_fold_kernel(const float* __restrict__ W,
                                 const float* __restrict__ b0,
                                 const float* __restrict__ stats,
                                 float* __restrict__ out,
                                 int Cin, int Cout, int K) {
  const int i = threadIdx.x;  // k*Cout + o
  if (i >= K * Cout) return;
  const int k = i / Cout, o = i % Cout;
  const float* sh = stats + 192;
  float acc = (k == 0) ? b0[o] : 0.f;
  for (int c = 0; c < Cin; c++) acc += sh[c] * W[((size_t)k * Cin + c) * Cout + o];
  out[i] = acc;
}

// ---------- CSR build ----------
__global__ __launch_bounds__(256) void hist_kernel(const int* __restrict__ rows,
                                                   int* __restrict__ cnt) {
  int i = blockIdx.x * blockDim.x + threadIdx.x;
  const int stride = gridDim.x * blockDim.x;
  for (; i < EN; i += stride) atomicAdd(&cnt[rows[i]], 1);
}

__global__ __launch_bounds__(256) void scan1_kernel(const int* __restrict__ cnt,
                                                    int* __restrict__ rp,
                                                    int* __restrict__ chunkSums) {
  __shared__ int sh[256];
  const int t = threadIdx.x;
  const int base = blockIdx.x * 2048 + t * 8;
  int vals[8]; int tot = 0;
#pragma unroll
  for (int i = 0; i < 8; i++) {
    int idx = base + i;
    int v = (idx < VN) ? cnt[idx] : 0;
    vals[i] = v; tot += v;
  }
  sh[t] = tot;
  __syncthreads();
  for (int off = 1; off < 256; off <<= 1) {
    int v = (t >= off) ? sh[t - off] : 0;
    __syncthreads();
    sh[t] += v;
    __syncthreads();
  }
  int run = sh[t] - tot;
#pragma unroll
  for (int i = 0; i < 8; i++) {
    int idx = base + i;
    if (idx < VN) rp[idx] = run;
    run += vals[i];
  }
  if (t == 255) chunkSums[blockIdx.x] = sh[255];
}

__global__ void scan2_kernel(const int* __restrict__ chunkSums,
                             int* __restrict__ chunkOff,
                             int* __restrict__ rp, int nChunks) {
  if (threadIdx.x == 0 && blockIdx.x == 0) {
    int off = 0;
    for (int j = 0; j < nChunks; j++) { chunkOff[j] = off; off += chunkSums[j]; }
    rp[VN] = off;
  }
}

__global__ __launch_bounds__(256) void scan3_kernel(int* __restrict__ rp,
                                                    const int* __restrict__ chunkOff,
                                                    int* __restrict__ fill) {
  int i = blockIdx.x * 256 + threadIdx.x;
  if (i < VN) {
    int v = rp[i] + chunkOff[i >> 11];
    rp[i] = v;
    fill[i] = v;
  }
}

__global__ __launch_bounds__(256) void fill_kernel(const int* __restrict__ rows,
                                                   const int* __restrict__ cols,
                                                   const float* __restrict__ lap,
                                                   int* __restrict__ fill,
                                                   int* __restrict__ cols_s,
                                                   float* __restrict__ vals_s) {
  int i = blockIdx.x * blockDim.x + threadIdx.x;
  const int stride = gridDim.x * blockDim.x;
  for (; i < EN; i += stride) {
    int r = rows[i];
    int pos = atomicAdd(&fill[r], 1);
    cols_s[pos] = cols[i];
    vals_s[pos] = lap[i];
  }
}

// ---------- rowsum[r] = sum of edge weights of row r (for BN-shift folding) ----------
__global__ __launch_bounds__(256) void row_sum_kernel(const int* __restrict__ rp,
                                                      const float* __restrict__ vs,
                                                      float* __restrict__ rowsum) {
  const int i = blockIdx.x * 256 + threadIdx.x;
  if (i >= VN) return;
  const int s = rp[i], e = rp[i + 1];
  float acc = 0.f;
  for (int j = s; j < e; j++) acc += vs[j];
  rowsum[i] = acc;
}

// ---------- SpMM: one wave per row, CSR gather ----------
// MODE: 0: Y = g; 1: Y = 2g - P; 2: Y = 2g + P; 3: Y = 2g - Q + P; 4: Y = g - Q + P
// AFFE (EPL=4, MODE 0): y = sc*g + rowsum[row]*sh (affine factored out of edge loop).
// AFFP (EPL=4, MODE 1): p -> sc*p + sh (row-level).
// P/Q row reads are single-use -> non-temporal (protect L3 for the gather-hot X).
template <int EPL, int MODE, bool AFFE, bool AFFP>
__global__ __launch_bounds__(256, 8) void spmm_kernel(const int* __restrict__ rp,
                                                   const int* __restrict__ cs,
                                                   const float* __restrict__ vs,
                                                   const unsigned short* __restrict__ X, int XS,
                                                   const unsigned short* __restrict__ P, int PS,
                                                   const unsigned short* __restrict__ Q, int QS,
                                                   unsigned short* __restrict__ Y, int YS,
                                                   const float* __restrict__ bnp,
                                                   const float* __restrict__ rowsum) {
  const int lane = threadIdx.x & 63;
  const int row = blockIdx.x * 4 + (threadIdx.x >> 6);
  const int start = rp[row], end = rp[row + 1];
  float acc[EPL];
#pragma unroll
  for (int j = 0; j < EPL; j++) acc[j] = 0.f;
  gather_accum<EPL>(start, end, cs, vs, X, XS, lane, acc);

  if constexpr (EPL == 4) {
    float4 sc, sh;
    if constexpr (AFFE || AFFP) {  // lane covers channels c0..c0+3 (layout [b][c], C=64)
      const int c0 = (lane * 4) & 63;
      sc = *reinterpret_cast<const float4*>(bnp + c0);
      sh = *reinterpret_cast<const float4*>(bnp + 64 + c0);
    }
    float r0 = acc[0], r1 = acc[1], r2 = acc[2], r3 = acc[3];
    if constexpr (AFFE) {
      const float rs = rowsum[row];
      r0 = sc.x * r0 + rs * sh.x;
      r1 = sc.y * r1 + rs * sh.y;
      r2 = sc.z * r2 + rs * sh.z;
      r3 = sc.w * r3 + rs * sh.w;
    }
    if constexpr (MODE == 1) {
      const u32x2 p = ntl_u32x2(P + (size_t)row * PS + lane * 4);
      float p0 = bf_lo(p.x), p1 = bf_hi(p.x), p2 = bf_lo(p.y), p3 = bf_hi(p.y);
      if constexpr (AFFP) {
        p0 = p0 * sc.x + sh.x;
        p1 = p1 * sc.y + sh.y;
        p2 = p2 * sc.z + sh.z;
        p3 = p3 * sc.w + sh.w;
      }
      r0 = 2.f * r0 - p0;
      r1 = 2.f * r1 - p1;
      r2 = 2.f * r2 - p2;
      r3 = 2.f * r3 - p3;
    }
    uint2 r;
    r.x = pack2(r0, r1);
    r.y = pack2(r2, r3);
    *reinterpret_cast<uint2*>(Y + (size_t)row * YS + lane * 4) = r;
  } else {
    float r0 = acc[0], r1 = acc[1];
    if constexpr (MODE == 1) {
      const unsigned int p = ntl_u32(P + (size_t)row * PS + lane * 2);
      r0 = 2.f * r0 - bf_lo(p);
      r1 = 2.f * r1 - bf_hi(p);
    } else if constexpr (MODE == 2) {
      const unsigned int p = ntl_u32(P + (size_t)row * PS + lane * 2);
      r0 = 2.f * r0 + bf_lo(p);
      r1 = 2.f * r1 + bf_hi(p);
    } else if constexpr (MODE == 3) {
      const unsigned int p = ntl_u32(P + (size_t)row * PS + lane * 2);
      const unsigned int qq = ntl_u32(Q + (size_t)row * QS + lane * 2);
      r0 = 2.f * r0 - bf_lo(qq) + bf_lo(p);
      r1 = 2.f * r1 - bf_hi(qq) + bf_hi(p);
    } else if constexpr (MODE == 4) {
      const unsigned int p = ntl_u32(P + (size_t)row * PS + lane * 2);
      const unsigned int qq = ntl_u32(Q + (size_t)row * QS + lane * 2);
      r0 = r0 - bf_lo(qq) + bf_lo(p);
      r1 = r1 - bf_hi(qq) + bf_hi(p);
    }
    *reinterpret_cast<unsigned int*>(Y + (size_t)row * YS + lane * 2) = pack2(r0, r1);
  }
}

// ---------- fused: x3 = 2*L(X2) - X1 (regs->LDS), OUT = relu(sum_k xk Wk + bias) ----------
// k=0 BN affine folded into packed weights/bias (h0).  Fragment reads (single-use
// streams) are non-temporal; the X2 gather stays cached.
// OUT may alias X0 (h0): fragment reads drained by __syncthreads before write.
template <int Cin, int Cout, int X0S, int X1S, int X2S>
__global__ __launch_bounds__(256, 8) void fused_cheb_kernel(const int* __restrict__ rp,
                                                         const int* __restrict__ cs,
                                                         const float* __restrict__ vs,
                                                         const unsigned short* __restrict__ X0,
                                                         const unsigned short* __restrict__ X1,
                                                         const unsigned short* __restrict__ X2,
                                                         unsigned short* __restrict__ OUT,
                                                         const unsigned short* __restrict__ Wb,
                                                         const float* __restrict__ Bias) {
  constexpr int EPL = Cin * 4 / 64;  // 2 or 4
  constexpr int ROWSH = Cin * 4;     // shorts per row in (B,C) layout
  __shared__ unsigned short t3s[4 * ROWSH];
  const int lane = threadIdx.x & 63;
  const int wv = threadIdx.x >> 6;
  const int row0 = blockIdx.x * 4;
  const int row = row0 + wv;

  // ---- phase 1: g = (L x2)[row] lane chunk; t3 = 2g - x1 -> LDS ----
  float g[EPL];
#pragma unroll
  for (int j = 0; j < EPL; j++) g[j] = 0.f;
  const int start = rp[row], end = rp[row + 1];
  gather_accum<EPL>(start, end, cs, vs, X2, X2S, lane, g);
  {
    unsigned int* tw = reinterpret_cast<unsigned int*>(t3s + wv * ROWSH);
    if constexpr (EPL == 4) {
      const u32x2 p = ntl_u32x2(X1 + (size_t)row * X1S + lane * 4);
      tw[lane * 2]     = pack2(2.f * g[0] - bf_lo(p.x), 2.f * g[1] - bf_hi(p.x));
      tw[lane * 2 + 1] = pack2(2.f * g[2] - bf_lo(p.y), 2.f * g[3] - bf_hi(p.y));
    } else {
      const unsigned int p = ntl_u32(X1 + (size_t)row * X1S + lane * 2);
      tw[lane] = pack2(2.f * g[0] - bf_lo(p), 2.f * g[1] - bf_hi(p));
    }
  }
  __syncthreads();  // all 4 rows' t3 visible to all waves

  // ---- phase 2: MFMA einsum ----
  constexpr int KC = Cin / 32;   // mfma K-chunks per Chebyshev order
  constexpr int T = Cout / 16;   // o-tiles
  const int col = lane & 15, quad = lane >> 4;
  const int t = wv % T;
  const int ar = col >> 2, ab = col & 3;  // A-operand m -> (row_local, batch)

  const unsigned short* xa0 = X0 + (size_t)(row0 + ar) * X0S + ab * Cin + quad * 8;
  const unsigned short* xa1 = X1 + (size_t)(row0 + ar) * X1S + ab * Cin + quad * 8;
  const unsigned short* xa2 = X2 + (size_t)(row0 + ar) * X2S + ab * Cin + quad * 8;
  const unsigned short* wb = Wb + (size_t)t * 512 + lane * 8;

  f32x4 acc = {0.f, 0.f, 0.f, 0.f};
#pragma unroll
  for (int kc = 0; kc < KC; kc++) {  // k = 0 (raw fragments; affine folded into Wb/Bias)
    const short8 af = ntl_s8(xa0 + kc * 32);
    const short8 bf = *reinterpret_cast<const short8*>(wb + (size_t)(0 * KC + kc) * T * 512);
    acc = __builtin_amdgcn_mfma_f32_16x16x32_bf16(af, bf, acc, 0, 0, 0);
  }
#pragma unroll
  for (int kc = 0; kc < KC; kc++) {  // k = 1
    const short8 af = ntl_s8(xa1 + kc * 32);
    const short8 bf = *reinterpret_cast<const short8*>(wb + (size_t)(1 * KC + kc) * T * 512);
    acc = __builtin_amdgcn_mfma_f32_16x16x32_bf16(af, bf, acc, 0, 0, 0);
  }
#pragma unroll
  for (int kc = 0; kc < KC; kc++) {  // k = 2
    const short8 af = ntl_s8(xa2 + kc * 32);
    const short8 bf = *reinterpret_cast<const short8*>(wb + (size_t)(2 * KC + kc) * T * 512);
    acc = __builtin_amdgcn_mfma_f32_16x16x32_bf16(af, bf, acc, 0, 0, 0);
  }
#pragma unroll
  for (int kc = 0; kc < KC; kc++) {  // k = 3 from LDS
    const short8 af = *reinterpret_cast<const short8*>(&t3s[ar * ROWSH + ab * Cin + kc * 32 + quad * 8]);
    const short8 bf = *reinterpret_cast<const short8*>(wb + (size_t)(3 * KC + kc) * T * 512);
    acc = __builtin_amdgcn_mfma_f32_16x16x32_bf16(af, bf, acc, 0, 0, 0);
  }
  __syncthreads();  // drain all waves' X0-fragment reads before in-place OUT write

  if (T == 4 || wv < 2) {
    const int og = t * 16 + col;
    const float bs = Bias[og];
#pragma unroll
    for (int r = 0; r < 4; r++) {
      const float val = fmaxf(acc[r] + bs, 0.f);   // relu stored (all consumers want relu)
      OUT[(size_t)(row0 + quad) * 256 + r * Cout + og] = f2bf(val);
    }
  }
}

// ---------- h1 Clenshaw GEMM: z_k = a . (sc.W_k) + zb_k, k = wave id ----------
// A reads are single-use streams -> non-temporal.
__global__ __launch_bounds__(256, 8) void gemm_z_kernel(const unsigned short* __restrict__ A,
                                                        const unsigned short* __restrict__ Wb,
                                                        const float* __restrict__ zb,
                                                        unsigned short* __restrict__ zA,
                                                        unsigned short* __restrict__ zB) {
  const int lane = threadIdx.x & 63;
  const int wv = threadIdx.x >> 6;     // = k (Chebyshev order)
  const int row0 = blockIdx.x * 4;
  const int col = lane & 15, quad = lane >> 4;
  const int ar = col >> 2, ab = col & 3;
  const unsigned short* xa = A + (size_t)(row0 + ar) * 256 + ab * 64 + quad * 8;
  const unsigned short* wb = Wb + (size_t)wv * 4 * 512 + lane * 8;   // [k][kc][t], KC=2, T=2
  unsigned short* zr = (wv < 2) ? (zA + (size_t)wv * VN * 128)
                                : (zB + (size_t)(wv - 2) * VN * 128);
  const short8 af0 = ntl_s8(xa);
  const short8 af1 = ntl_s8(xa + 32);
#pragma unroll
  for (int t = 0; t < 2; t++) {
    f32x4 acc = {0.f, 0.f, 0.f, 0.f};
    const short8 bf0 = *reinterpret_cast<const short8*>(wb + (size_t)(0 * 2 + t) * 512);
    const short8 bf1 = *reinterpret_cast<const short8*>(wb + (size_t)(1 * 2 + t) * 512);
    acc = __builtin_amdgcn_mfma_f32_16x16x32_bf16(af0, bf0, acc, 0, 0, 0);
    acc = __builtin_amdgcn_mfma_f32_16x16x32_bf16(af1, bf1, acc, 0, 0, 0);
    const int og = t * 16 + col;
    const float bs = zb[wv * 32 + og];
#pragma unroll
    for (int r = 0; r < 4; r++) {
      zr[(size_t)(row0 + quad) * 128 + r * 32 + og] = f2bf(acc[r] + bs);
    }
  }
}

// ---------- stats of SRC (already relu'd): rows (V)[b][o] stride 256, o in 0..63 ----------
// (kept cache-normal: this streaming read doubles as an L3 prefetch of A right
//  before the heaviest gather pass)
__global__ __launch_bounds__(256) void stats_out_kernel(const unsigned short* __restrict__ SRC,
                                                        float* __restrict__ stats) {
  const int tid = threadIdx.x;  // tid = b*64 + o
  const int per = (VN + gridDim.x - 1) / gridDim.x;
  const int v0 = blockIdx.x * per;
  const int v1 = (v0 + per < VN) ? (v0 + per) : VN;
  float s = 0.f, s2 = 0.f;
  for (int v = v0; v < v1; v++) {
    float val = bf1(SRC[(size_t)v * 256 + tid]);
    s += val; s2 += val * val;
  }
  __shared__ float r1[256], r2[256];
  r1[tid] = s; r2[tid] = s2;
  __syncthreads();
  if (tid < 64) {  // sum the 4 batches for channel o = tid
    float a = r1[tid] + r1[tid + 64] + r1[tid + 128] + r1[tid + 192];
    float b = r2[tid] + r2[tid + 64] + r2[tid + 128] + r2[tid + 192];
    atomicAdd(&stats[tid], a);
    atomicAdd(&stats[64 + tid], b);
  }
}

// ---------- final: out[b,o,v] = relu(SRC[v,b,o] + xn[v,b,o]) ----------
// All reads/writes single-use -> fully non-temporal.
__global__ __launch_bounds__(256) void final_kernel(const unsigned short* __restrict__ SRC,
                                                    const unsigned short* __restrict__ xn,
                                                    float* __restrict__ out) {
  const int lane = threadIdx.x & 63;
  const int grp = threadIdx.x >> 6;  // 0..3
  const int v = blockIdx.x * 64 + lane;
  if (v >= VN) return;
  for (int ob = grp; ob < 128; ob += 4) {  // ob = b*32 + o
    float val = bf1(__builtin_nontemporal_load(SRC + (size_t)v * 128 + ob)) +
                bf1(__builtin_nontemporal_load(xn + (size_t)v * 128 + ob));
    val = fmaxf(val, 0.f);
    __builtin_nontemporal_store(val, out + (size_t)ob * VN + v);
  }
}

// ---------- workspace layout (~193 MB) ----------
static constexpr size_t align_up(size_t x) { return (x + 255) & ~(size_t)255; }
static constexpr size_t OFF_RP    = 0;
static constexpr size_t OFF_FILL  = align_up(OFF_RP + (size_t)(VN + 1) * 4);   // doubles as rowsum after CSR build
static constexpr size_t OFF_CHS   = align_up(OFF_FILL + (size_t)VN * 4);
static constexpr size_t OFF_CHO   = align_up(OFF_CHS + 256);
static constexpr size_t OFF_STATS = align_up(OFF_CHO + 256);
static constexpr size_t OFF_BIAS  = align_up(OFF_STATS + 1024);     // 64 (h0) + 128 (h1 zb) floats
static constexpr size_t OFF_WP    = align_up(OFF_BIAS + 1024);      // 32768 shorts = 64 KB
static constexpr size_t OFF_CS    = align_up(OFF_WP + 32768 * 2);
static constexpr size_t OFF_VS    = align_up(OFF_CS + (size_t)EN * 4);
static constexpr size_t OFF_XN    = align_up(OFF_VS + (size_t)EN * 4);
static constexpr size_t OFF_XL    = align_up(OFF_XN + (size_t)VN * 128 * 2);
static constexpr size_t OFF_A     = align_up(OFF_XL + (size_t)VN * 256 * 2);
static constexpr size_t OFF_B     = align_up(OFF_A + (size_t)VN * 256 * 2);
static constexpr size_t OFF_END   = OFF_B + (size_t)VN * 256 * 2;

extern "C" void kernel_launch(void* const* d_in, const int* in_sizes, int n_in,
                              void* d_out, int out_size, void* d_ws, size_t ws_size,
                              hipStream_t stream) {
  if (ws_size < OFF_END) return;  // diagnostic guard

  const float* x       = (const float*)d_in[0];
  const int*   rows    = (const int*)d_in[1];
  const int*   cols    = rows + EN;
  const float* lap     = (const float*)d_in[2];
  const float* in_bn_g = (const float*)d_in[3];
  const float* in_bn_b = (const float*)d_in[4];
  const float* in_w    = (const float*)d_in[5];
  const float* in_b    = (const float*)d_in[6];
  const float* h0_bn_g = (const float*)d_in[7];
  const float* h0_bn_b = (const float*)d_in[8];
  const float* h0_w    = (const float*)d_in[9];
  const float* h0_b    = (const float*)d_in[10];
  const float* h1_bn_g = (const float*)d_in[11];
  const float* h1_bn_b = (const float*)d_in[12];
  const float* h1_w    = (const float*)d_in[13];
  const float* h1_b    = (const float*)d_in[14];
  float* outp = (float*)d_out;

  char* ws = (char*)d_ws;
  int*   rp     = (int*)(ws + OFF_RP);
  int*   fill   = (int*)(ws + OFF_FILL);
  float* rowsum = (float*)(ws + OFF_FILL);   // overlays fill (dead after CSR build)
  int*   chS    = (int*)(ws + OFF_CHS);
  int*   chO    = (int*)(ws + OFF_CHO);
  float* stats  = (float*)(ws + OFF_STATS);
  float* biasF  = (float*)(ws + OFF_BIAS);   // [0..63] h0 folded bias; [64..191] h1 zb
  unsigned short* wbIn = (unsigned short*)(ws + OFF_WP);      // 8192 shorts
  unsigned short* wbH0 = wbIn + 8192;                         // 16384 shorts
  unsigned short* wbH1 = wbH0 + 16384;                        // 8192 shorts
  int*   cs     = (int*)(ws + OFF_CS);
  float* vs     = (float*)(ws + OFF_VS);
  unsigned short* xn = (unsigned short*)(ws + OFF_XN);
  unsigned short* XL = (unsigned short*)(ws + OFF_XL);
  unsigned short* A  = (unsigned short*)(ws + OFF_A);
  unsigned short* B  = (unsigned short*)(ws + OFF_B);
  const float* bnp = stats + 128;  // {sc[0..63], sh[0..63]}

  const int nChunks = (VN + 2047) / 2048;  // 49

  // ---- W pre-pack (layer "in" only; h0/h1 packs fold BN and launch after stats) ----
  pack_wb_kernel<<<32, 256, 0, stream>>>(in_w, wbIn, 32, 64, nullptr, 0);

  // ---- input BN stats + normalize/transpose ----
  hipMemsetAsync(stats, 0, 1024, stream);
  stats_x_kernel<<<1024, 256, 0, stream>>>(x, stats);
  finalize_stats_kernel<<<1, 64, 0, stream>>>(stats, in_bn_g, in_bn_b, 32);
  bn_transpose_kernel<<<1563, 128, 0, stream>>>(x, stats, xn);

  // ---- CSR build ----
  hipMemsetAsync(fill, 0, (size_t)VN * 4, stream);
  hist_kernel<<<2048, 256, 0, stream>>>(rows, fill);
  scan1_kernel<<<nChunks, 256, 0, stream>>>(fill, rp, chS);
  scan2_kernel<<<1, 64, 0, stream>>>(chS, chO, rp, nChunks);
  scan3_kernel<<<(VN + 255) / 256, 256, 0, stream>>>(rp, chO, fill);
  fill_kernel<<<2048, 256, 0, stream>>>(rows, cols, lap, fill, cs, vs);
  row_sum_kernel<<<(VN + 255) / 256, 256, 0, stream>>>(rp, vs, rowsum);  // fill now dead

  // ---- layer "in": Cin=32, Cout=64. x1/x2 compact (stride 128) in XL halves ----
  unsigned short* XLa = XL;                       // x1, VN*128 shorts
  unsigned short* XLb = XL + (size_t)VN * 128;    // x2
  spmm_kernel<2, 0, false, false><<<VN / 4, 256, 0, stream>>>(
      rp, cs, vs, xn, 128, nullptr, 0, nullptr, 0, XLa, 128, nullptr, nullptr);
  spmm_kernel<2, 1, false, false><<<VN / 4, 256, 0, stream>>>(
      rp, cs, vs, XLa, 128, xn, 128, nullptr, 0, XLb, 128, nullptr, nullptr);
  fused_cheb_kernel<32, 64, 128, 128, 128><<<VN / 4, 256, 0, stream>>>(
      rp, cs, vs, xn, XLa, XLb, A, wbIn, in_b);   // A := relu(out_in)
  hipMemsetAsync(stats, 0, 1024, stream);
  stats_out_kernel<<<256, 256, 0, stream>>>(A, stats);
  finalize_stats_kernel<<<1, 64, 0, stream>>>(stats, h0_bn_g, h0_bn_b, 64);

  // ---- h0 weight pack with BN fold: sc into k=0 weights, sh.W0 into bias ----
  pack_wb_kernel<<<64, 256, 0, stream>>>(h0_w, wbH0, 64, 64, bnp, 0x1);
  bias_fold_kernel<<<1, 128, 0, stream>>>(h0_w, h0_b, stats, biasF, 64, 64, 1);

  // ---- layer h0: Cin=64, Cout=64; A holds relu'd input, BN affine out of edge loops ----
  spmm_kernel<4, 0, true, false><<<VN / 4, 256, 0, stream>>>(
      rp, cs, vs, A, 256, nullptr, 0, nullptr, 0, XL, 256, bnp, rowsum);  // x1 = sc*L(relu) + rowsum*sh
  spmm_kernel<4, 1, false, true><<<VN / 4, 256, 0, stream>>>(
      rp, cs, vs, XL, 256, A, 256, nullptr, 0, B, 256, bnp, nullptr);     // x2 = 2 L x1 - affine(A)
  fused_cheb_kernel<64, 64, 256, 256, 256><<<VN / 4, 256, 0, stream>>>(
      rp, cs, vs, A, XL, B, A, wbH0, biasF);      // A := relu(out_h0), k=0 folded
  hipMemsetAsync(stats, 0, 1024, stream);
  stats_out_kernel<<<256, 256, 0, stream>>>(A, stats);
  finalize_stats_kernel<<<1, 64, 0, stream>>>(stats, h1_bn_g, h1_bn_b, 64);

  // ---- h1 weight pack with BN fold: sc into ALL k, per-k bias zb = sh.Wk (+b for k0) ----
  pack_wb_kernel<<<32, 256, 0, stream>>>(h1_w, wbH1, 64, 32, bnp, 0xF);
  bias_fold_kernel<<<1, 128, 0, stream>>>(h1_w, h1_b, stats, biasF + 64, 64, 32, 4);

  // ---- layer h1: Cin=64, Cout=32 via Clenshaw on 32-channel z_k ----
  {
    unsigned short* z0 = XL;
    unsigned short* z1 = XL + (size_t)VN * 128;
    unsigned short* z2 = B;
    unsigned short* z3 = B + (size_t)VN * 128;
    gemm_z_kernel<<<VN / 4, 256, 0, stream>>>(A, wbH1, biasF + 64, z0, z2);
    spmm_kernel<2, 2, false, false><<<VN / 4, 256, 0, stream>>>(
        rp, cs, vs, z3, 128, z2, 128, nullptr, 0, z2, 128, nullptr, nullptr);
    spmm_kernel<2, 3, false, false><<<VN / 4, 256, 0, stream>>>(
        rp, cs, vs, z2, 128, z1, 128, z3, 128, z1, 128, nullptr, nullptr);
    spmm_kernel<2, 4, false, false><<<VN / 4, 256, 0, stream>>>(
        rp, cs, vs, z1, 128, z0, 128, z2, 128, z0, 128, nullptr, nullptr);
    // ---- residual + relu + transpose to (B,32,V) ----
    final_kernel<<<1563, 256, 0, stream>>>(z0, xn, outp);
  }
}

// Round 6
// 1541.193 us; speedup vs baseline: 1.2160x; 1.2160x over previous
//
#include <hip/hip_runtime.h>
#include <cstdint>
#include <cstddef>

#define VN 100000
#define EN 1600000
static constexpr float BN_EPS_F = 1e-5f;
static constexpr float INV_N = 1.0f / 400000.0f;   // B*V = 4*100000

using short8 = __attribute__((ext_vector_type(8))) short;
using f32x4  = __attribute__((ext_vector_type(4))) float;

// ---------- bf16 helpers (manual, RTNE) ----------
__device__ __forceinline__ float bf_lo(unsigned int p) {
  return __builtin_bit_cast(float, p << 16);
}
__device__ __forceinline__ float bf_hi(unsigned int p) {
  return __builtin_bit_cast(float, p & 0xffff0000u);
}
__device__ __forceinline__ float bf1(unsigned short u) {
  return __builtin_bit_cast(float, ((unsigned int)u) << 16);
}
__device__ __forceinline__ unsigned short f2bf(float f) {
  unsigned int x = __builtin_bit_cast(unsigned int, f);
  x += 0x7fffu + ((x >> 16) & 1u);
  return (unsigned short)(x >> 16);
}
__device__ __forceinline__ unsigned int pack2(float a, float b) {
  return (unsigned int)f2bf(a) | ((unsigned int)f2bf(b) << 16);
}

// ---------- CSR row gather+accumulate, 8/4/1-edge unroll ----------
// start/end/e are SGPR-resident (caller passes readfirstlane'd row), so cs/vs
// loads scalarize to s_load and gather addresses are SGPR-base + lane offset.
template <int EPL>
__device__ __forceinline__ void gather_accum(int start, int end,
    const int* __restrict__ cs, const float* __restrict__ vs,
    const unsigned short* __restrict__ X, int XS, int lane, float* acc) {
  int e = start;
  if constexpr (EPL == 4) {
    for (; e + 8 <= end; e += 8) {
      uint2 q[8]; float w[8];
#pragma unroll
      for (int u = 0; u < 8; u++) {
        q[u] = *reinterpret_cast<const uint2*>(X + (size_t)cs[e + u] * XS + lane * 4);
        w[u] = vs[e + u];
      }
#pragma unroll
      for (int u = 0; u < 8; u++) {
        acc[0] += w[u] * bf_lo(q[u].x);
        acc[1] += w[u] * bf_hi(q[u].x);
        acc[2] += w[u] * bf_lo(q[u].y);
        acc[3] += w[u] * bf_hi(q[u].y);
      }
    }
    for (; e + 4 <= end; e += 4) {
      uint2 q[4]; float w[4];
#pragma unroll
      for (int u = 0; u < 4; u++) {
        q[u] = *reinterpret_cast<const uint2*>(X + (size_t)cs[e + u] * XS + lane * 4);
        w[u] = vs[e + u];
      }
#pragma unroll
      for (int u = 0; u < 4; u++) {
        acc[0] += w[u] * bf_lo(q[u].x);
        acc[1] += w[u] * bf_hi(q[u].x);
        acc[2] += w[u] * bf_lo(q[u].y);
        acc[3] += w[u] * bf_hi(q[u].y);
      }
    }
    for (; e < end; e++) {
      const uint2 q = *reinterpret_cast<const uint2*>(X + (size_t)cs[e] * XS + lane * 4);
      const float w = vs[e];
      acc[0] += w * bf_lo(q.x);
      acc[1] += w * bf_hi(q.x);
      acc[2] += w * bf_lo(q.y);
      acc[3] += w * bf_hi(q.y);
    }
  } else {
    for (; e + 8 <= end; e += 8) {
      unsigned int q[8]; float w[8];
#pragma unroll
      for (int u = 0; u < 8; u++) {
        q[u] = *reinterpret_cast<const unsigned int*>(X + (size_t)cs[e + u] * XS + lane * 2);
        w[u] = vs[e + u];
      }
#pragma unroll
      for (int u = 0; u < 8; u++) {
        acc[0] += w[u] * bf_lo(q[u]);
        acc[1] += w[u] * bf_hi(q[u]);
      }
    }
    for (; e + 4 <= end; e += 4) {
      unsigned int q[4]; float w[4];
#pragma unroll
      for (int u = 0; u < 4; u++) {
        q[u] = *reinterpret_cast<const unsigned int*>(X + (size_t)cs[e + u] * XS + lane * 2);
        w[u] = vs[e + u];
      }
#pragma unroll
      for (int u = 0; u < 4; u++) {
        acc[0] += w[u] * bf_lo(q[u]);
        acc[1] += w[u] * bf_hi(q[u]);
      }
    }
    for (; e < end; e++) {
      const unsigned int q = *reinterpret_cast<const unsigned int*>(X + (size_t)cs[e] * XS + lane * 2);
      const float w = vs[e];
      acc[0] += w * bf_lo(q);
      acc[1] += w * bf_hi(q);
    }
  }
}

// ---------- K1: per-channel sum/sumsq of input x (B,32,V) fp32 ----------
__global__ __launch_bounds__(256) void stats_x_kernel(const float* __restrict__ x,
                                                      float* __restrict__ stats) {
  const int p = blockIdx.x & 127;      // plane = (b,c)
  const int chunk = blockIdx.x >> 7;   // 0..7
  const int c = p & 31, b = p >> 5;
  const float* base = x + ((size_t)b * 32 + c) * VN + chunk * 12500;
  float s = 0.f, s2 = 0.f;
  for (int i = threadIdx.x; i < 12500; i += 256) {
    float v = base[i];
    s += v; s2 += v * v;
  }
  __shared__ float r1[256], r2[256];
  r1[threadIdx.x] = s; r2[threadIdx.x] = s2;
  __syncthreads();
  for (int off = 128; off > 0; off >>= 1) {
    if (threadIdx.x < off) {
      r1[threadIdx.x] += r1[threadIdx.x + off];
      r2[threadIdx.x] += r2[threadIdx.x + off];
    }
    __syncthreads();
  }
  if (threadIdx.x == 0) {
    atomicAdd(&stats[c], r1[0]);
    atomicAdd(&stats[64 + c], r2[0]);
  }
}

__global__ void finalize_stats_kernel(float* __restrict__ stats,
                                      const float* __restrict__ g,
                                      const float* __restrict__ beta, int C) {
  int c = threadIdx.x;
  if (c < C) {
    float m = stats[c] * INV_N;
    float var = stats[64 + c] * INV_N - m * m;
    float sc = g[c] * rsqrtf(var + BN_EPS_F);
    stats[128 + c] = sc;
    stats[192 + c] = beta[c] - m * sc;
  }
}

// ---------- K2: normalize input + transpose (B,32,V)->(V, B=4, C=32) bf16, stride 128 ----------
__global__ __launch_bounds__(128) void bn_transpose_kernel(const float* __restrict__ x,
                                                           const float* __restrict__ stats,
                                                           unsigned short* __restrict__ xn) {
  const int tid = threadIdx.x;       // tid = b*32 + c
  const int b = tid >> 5, c = tid & 31;
  const int v0 = blockIdx.x * 64;
  const float sc = stats[128 + c], sh = stats[192 + c];
  const float* src = x + ((size_t)b * 32 + c) * VN;
  for (int i = 0; i < 64; i++) {
    int v = v0 + i;
    if (v < VN) xn[(size_t)v * 128 + tid] = f2bf(sc * src[v] + sh);
  }
}

// ---------- W pre-pack: fp32 (K,Cin,Cout) -> bf16 MFMA B-fragment order ----------
// scale != nullptr: fold per-channel scale[c] into W[k][c][o] for k with (kmask>>k)&1
__global__ __launch_bounds__(256) void pack_wb_kernel(const float* __restrict__ W,
                                                      unsigned short* __restrict__ Wb,
                                                      int Cin, int Cout,
                                                      const float* __restrict__ scale,
                                                      int kmask) {
  const int i = blockIdx.x * 256 + threadIdx.x;
  const int KC = Cin >> 5, T = Cout >> 4;
  const int tot = 4 * KC * T * 512;
  if (i >= tot) return;
  const int j = i & 7;
  const int l = (i >> 3) & 63;
  const int rem = i >> 9;
  const int t = rem % T;
  const int kc = (rem / T) % KC;
  const int k = rem / (T * KC);
  const int c = kc * 32 + (l >> 4) * 8 + j;
  const int o = t * 16 + (l & 15);
  float w = W[((size_t)k * Cin + c) * Cout + o];
  if (scale != nullptr && ((kmask >> k) & 1)) w *= scale[c];
  Wb[i] = f2bf(w);
}

// ---------- bias fold: out[k*Cout+o] = (k==0 ? b0[o] : 0) + sum_c sh[c]*W[k][c][o] ----------
__global__ void bias_fold_kernel(const float* __restrict__ W,
                                 const float* __restrict__ b0,
                                 const float* __restrict__ stats,
                                 float* __restrict__ out,
                                 int Cin, int Cout, int K) {
  const int i = threadIdx.x;  // k*Cout + o
  if (i >= K * Cout) return;
  const int k = i / Cout, o = i % Cout;
  const float* sh = stats + 192;
  float acc = (k == 0) ? b0[o] : 0.f;
  for (int c = 0; c < Cin; c++) acc += sh[c] * W[((size_t)k * Cin + c) * Cout + o];
  out[i] = acc;
}

// ---------- CSR build ----------
__global__ __launch_bounds__(256) void hist_kernel(const int* __restrict__ rows,
                                                   int* __restrict__ cnt) {
  int i = blockIdx.x * blockDim.x + threadIdx.x;
  const int stride = gridDim.x * blockDim.x;
  for (; i < EN; i += stride) atomicAdd(&cnt[rows[i]], 1);
}

__global__ __launch_bounds__(256) void scan1_kernel(const int* __restrict__ cnt,
                                                    int* __restrict__ rp,
                                                    int* __restrict__ chunkSums) {
  __shared__ int sh[256];
  const int t = threadIdx.x;
  const int base = blockIdx.x * 2048 + t * 8;
  int vals[8]; int tot = 0;
#pragma unroll
  for (int i = 0; i < 8; i++) {
    int idx = base + i;
    int v = (idx < VN) ? cnt[idx] : 0;
    vals[i] = v; tot += v;
  }
  sh[t] = tot;
  __syncthreads();
  for (int off = 1; off < 256; off <<= 1) {
    int v = (t >= off) ? sh[t - off] : 0;
    __syncthreads();
    sh[t] += v;
    __syncthreads();
  }
  int run = sh[t] - tot;
#pragma unroll
  for (int i = 0; i < 8; i++) {
    int idx = base + i;
    if (idx < VN) rp[idx] = run;
    run += vals[i];
  }
  if (t == 255) chunkSums[blockIdx.x] = sh[255];
}

__global__ void scan2_kernel(const int* __restrict__ chunkSums,
                             int* __restrict__ chunkOff,
                             int* __restrict__ rp, int nChunks) {
  if (threadIdx.x == 0 && blockIdx.x == 0) {
    int off = 0;
    for (int j = 0; j < nChunks; j++) { chunkOff[j] = off; off += chunkSums[j]; }
    rp[VN] = off;
  }
}

__global__ __launch_bounds__(256) void scan3_kernel(int* __restrict__ rp,
                                                    const int* __restrict__ chunkOff,
                                                    int* __restrict__ fill) {
  int i = blockIdx.x * 256 + threadIdx.x;
  if (i < VN) {
    int v = rp[i] + chunkOff[i >> 11];
    rp[i] = v;
    fill[i] = v;
  }
}

__global__ __launch_bounds__(256) void fill_kernel(const int* __restrict__ rows,
                                                   const int* __restrict__ cols,
                                                   const float* __restrict__ lap,
                                                   int* __restrict__ fill,
                                                   int* __restrict__ cols_s,
                                                   float* __restrict__ vals_s) {
  int i = blockIdx.x * blockDim.x + threadIdx.x;
  const int stride = gridDim.x * blockDim.x;
  for (; i < EN; i += stride) {
    int r = rows[i];
    int pos = atomicAdd(&fill[r], 1);
    cols_s[pos] = cols[i];
    vals_s[pos] = lap[i];
  }
}

// ---------- rowsum[r] = sum of edge weights of row r (for BN-shift folding) ----------
__global__ __launch_bounds__(256) void row_sum_kernel(const int* __restrict__ rp,
                                                      const float* __restrict__ vs,
                                                      float* __restrict__ rowsum) {
  const int i = blockIdx.x * 256 + threadIdx.x;
  if (i >= VN) return;
  const int s = rp[i], e = rp[i + 1];
  float acc = 0.f;
  for (int j = s; j < e; j++) acc += vs[j];
  rowsum[i] = acc;
}

// ---------- SpMM: one wave per row, CSR gather ----------
// MODE: 0: Y = g; 1: Y = 2g - P; 2: Y = 2g + P; 3: Y = 2g - Q + P; 4: Y = g - Q + P
// AFFE (EPL=4, MODE 0): y = sc*g + rowsum[row]*sh (affine factored out of edge loop).
// AFFP (EPL=4, MODE 1): p -> sc*p + sh (row-level).
// row forced wave-uniform (readfirstlane) -> scalar rp/cs/vs loads.
template <int EPL, int MODE, bool AFFE, bool AFFP>
__global__ __launch_bounds__(256, 8) void spmm_kernel(const int* __restrict__ rp,
                                                   const int* __restrict__ cs,
                                                   const float* __restrict__ vs,
                                                   const unsigned short* __restrict__ X, int XS,
                                                   const unsigned short* __restrict__ P, int PS,
                                                   const unsigned short* __restrict__ Q, int QS,
                                                   unsigned short* __restrict__ Y, int YS,
                                                   const float* __restrict__ bnp,
                                                   const float* __restrict__ rowsum) {
  const int lane = threadIdx.x & 63;
  const int row = __builtin_amdgcn_readfirstlane(blockIdx.x * 4 + (threadIdx.x >> 6));
  const int start = rp[row], end = rp[row + 1];
  float acc[EPL];
#pragma unroll
  for (int j = 0; j < EPL; j++) acc[j] = 0.f;
  gather_accum<EPL>(start, end, cs, vs, X, XS, lane, acc);

  if constexpr (EPL == 4) {
    float4 sc, sh;
    if constexpr (AFFE || AFFP) {  // lane covers channels c0..c0+3 (layout [b][c], C=64)
      const int c0 = (lane * 4) & 63;
      sc = *reinterpret_cast<const float4*>(bnp + c0);
      sh = *reinterpret_cast<const float4*>(bnp + 64 + c0);
    }
    float r0 = acc[0], r1 = acc[1], r2 = acc[2], r3 = acc[3];
    if constexpr (AFFE) {
      const float rs = rowsum[row];
      r0 = sc.x * r0 + rs * sh.x;
      r1 = sc.y * r1 + rs * sh.y;
      r2 = sc.z * r2 + rs * sh.z;
      r3 = sc.w * r3 + rs * sh.w;
    }
    if constexpr (MODE == 1) {
      const uint2 p = *reinterpret_cast<const uint2*>(P + (size_t)row * PS + lane * 4);
      float p0 = bf_lo(p.x), p1 = bf_hi(p.x), p2 = bf_lo(p.y), p3 = bf_hi(p.y);
      if constexpr (AFFP) {
        p0 = p0 * sc.x + sh.x;
        p1 = p1 * sc.y + sh.y;
        p2 = p2 * sc.z + sh.z;
        p3 = p3 * sc.w + sh.w;
      }
      r0 = 2.f * r0 - p0;
      r1 = 2.f * r1 - p1;
      r2 = 2.f * r2 - p2;
      r3 = 2.f * r3 - p3;
    }
    uint2 r;
    r.x = pack2(r0, r1);
    r.y = pack2(r2, r3);
    *reinterpret_cast<uint2*>(Y + (size_t)row * YS + lane * 4) = r;
  } else {
    float r0 = acc[0], r1 = acc[1];
    if constexpr (MODE == 1) {
      const unsigned int p = *reinterpret_cast<const unsigned int*>(P + (size_t)row * PS + lane * 2);
      r0 = 2.f * r0 - bf_lo(p);
      r1 = 2.f * r1 - bf_hi(p);
    } else if constexpr (MODE == 2) {
      const unsigned int p = *reinterpret_cast<const unsigned int*>(P + (size_t)row * PS + lane * 2);
      r0 = 2.f * r0 + bf_lo(p);
      r1 = 2.f * r1 + bf_hi(p);
    } else if constexpr (MODE == 3) {
      const unsigned int p = *reinterpret_cast<const unsigned int*>(P + (size_t)row * PS + lane * 2);
      const unsigned int qq = *reinterpret_cast<const unsigned int*>(Q + (size_t)row * QS + lane * 2);
      r0 = 2.f * r0 - bf_lo(qq) + bf_lo(p);
      r1 = 2.f * r1 - bf_hi(qq) + bf_hi(p);
    } else if constexpr (MODE == 4) {
      const unsigned int p = *reinterpret_cast<const unsigned int*>(P + (size_t)row * PS + lane * 2);
      const unsigned int qq = *reinterpret_cast<const unsigned int*>(Q + (size_t)row * QS + lane * 2);
      r0 = r0 - bf_lo(qq) + bf_lo(p);
      r1 = r1 - bf_hi(qq) + bf_hi(p);
    }
    *reinterpret_cast<unsigned int*>(Y + (size_t)row * YS + lane * 2) = pack2(r0, r1);
  }
}

// ---------- fused: x3 = 2*L(X2) - X1 (regs->LDS), OUT = relu(sum_k xk Wk + bias) ----------
// k=0 BN affine folded into packed weights/bias (h0).
// OUT may alias X0 (h0): fragment reads drained by __syncthreads before write.
template <int Cin, int Cout, int X0S, int X1S, int X2S>
__global__ __launch_bounds__(256, 8) void fused_cheb_kernel(const int* __restrict__ rp,
                                                         const int* __restrict__ cs,
                                                         const float* __restrict__ vs,
                                                         const unsigned short* __restrict__ X0,
                                                         const unsigned short* __restrict__ X1,
                                                         const unsigned short* __restrict__ X2,
                                                         unsigned short* __restrict__ OUT,
                                                         const unsigned short* __restrict__ Wb,
                                                         const float* __restrict__ Bias) {
  constexpr int EPL = Cin * 4 / 64;  // 2 or 4
  constexpr int ROWSH = Cin * 4;     // shorts per row in (B,C) layout
  __shared__ unsigned short t3s[4 * ROWSH];
  const int lane = threadIdx.x & 63;
  const int wv = threadIdx.x >> 6;
  const int row0 = blockIdx.x * 4;
  const int row = __builtin_amdgcn_readfirstlane(row0 + wv);

  // ---- phase 1: g = (L x2)[row] lane chunk; t3 = 2g - x1 -> LDS ----
  float g[EPL];
#pragma unroll
  for (int j = 0; j < EPL; j++) g[j] = 0.f;
  const int start = rp[row], end = rp[row + 1];
  gather_accum<EPL>(start, end, cs, vs, X2, X2S, lane, g);
  {
    unsigned int* tw = reinterpret_cast<unsigned int*>(t3s + wv * ROWSH);
    if constexpr (EPL == 4) {
      const uint2 p = *reinterpret_cast<const uint2*>(X1 + (size_t)row * X1S + lane * 4);
      tw[lane * 2]     = pack2(2.f * g[0] - bf_lo(p.x), 2.f * g[1] - bf_hi(p.x));
      tw[lane * 2 + 1] = pack2(2.f * g[2] - bf_lo(p.y), 2.f * g[3] - bf_hi(p.y));
    } else {
      const unsigned int p = *reinterpret_cast<const unsigned int*>(X1 + (size_t)row * X1S + lane * 2);
      tw[lane] = pack2(2.f * g[0] - bf_lo(p), 2.f * g[1] - bf_hi(p));
    }
  }
  __syncthreads();  // all 4 rows' t3 visible to all waves

  // ---- phase 2: MFMA einsum ----
  constexpr int KC = Cin / 32;   // mfma K-chunks per Chebyshev order
  constexpr int T = Cout / 16;   // o-tiles
  const int col = lane & 15, quad = lane >> 4;
  const int t = wv % T;
  const int ar = col >> 2, ab = col & 3;  // A-operand m -> (row_local, batch)

  const unsigned short* xa0 = X0 + (size_t)(row0 + ar) * X0S + ab * Cin + quad * 8;
  const unsigned short* xa1 = X1 + (size_t)(row0 + ar) * X1S + ab * Cin + quad * 8;
  const unsigned short* xa2 = X2 + (size_t)(row0 + ar) * X2S + ab * Cin + quad * 8;
  const unsigned short* wb = Wb + (size_t)t * 512 + lane * 8;

  f32x4 acc = {0.f, 0.f, 0.f, 0.f};
#pragma unroll
  for (int kc = 0; kc < KC; kc++) {  // k = 0 (raw fragments; affine folded into Wb/Bias)
    const short8 af = *reinterpret_cast<const short8*>(xa0 + kc * 32);
    const short8 bf = *reinterpret_cast<const short8*>(wb + (size_t)(0 * KC + kc) * T * 512);
    acc = __builtin_amdgcn_mfma_f32_16x16x32_bf16(af, bf, acc, 0, 0, 0);
  }
#pragma unroll
  for (int kc = 0; kc < KC; kc++) {  // k = 1
    const short8 af = *reinterpret_cast<const short8*>(xa1 + kc * 32);
    const short8 bf = *reinterpret_cast<const short8*>(wb + (size_t)(1 * KC + kc) * T * 512);
    acc = __builtin_amdgcn_mfma_f32_16x16x32_bf16(af, bf, acc, 0, 0, 0);
  }
#pragma unroll
  for (int kc = 0; kc < KC; kc++) {  // k = 2
    const short8 af = *reinterpret_cast<const short8*>(xa2 + kc * 32);
    const short8 bf = *reinterpret_cast<const short8*>(wb + (size_t)(2 * KC + kc) * T * 512);
    acc = __builtin_amdgcn_mfma_f32_16x16x32_bf16(af, bf, acc, 0, 0, 0);
  }
#pragma unroll
  for (int kc = 0; kc < KC; kc++) {  // k = 3 from LDS
    const short8 af = *reinterpret_cast<const short8*>(&t3s[ar * ROWSH + ab * Cin + kc * 32 + quad * 8]);
    const short8 bf = *reinterpret_cast<const short8*>(wb + (size_t)(3 * KC + kc) * T * 512);
    acc = __builtin_amdgcn_mfma_f32_16x16x32_bf16(af, bf, acc, 0, 0, 0);
  }
  __syncthreads();  // drain all waves' X0-fragment reads before in-place OUT write

  if (T == 4 || wv < 2) {
    const int og = t * 16 + col;
    const float bs = Bias[og];
#pragma unroll
    for (int r = 0; r < 4; r++) {
      const float val = fmaxf(acc[r] + bs, 0.f);   // relu stored (all consumers want relu)
      OUT[(size_t)(row0 + quad) * 256 + r * Cout + og] = f2bf(val);
    }
  }
}

// ---------- h1 Clenshaw GEMM: z_k = a . (sc.W_k) + zb_k, k = wave id ----------
__global__ __launch_bounds__(256, 8) void gemm_z_kernel(const unsigned short* __restrict__ A,
                                                        const unsigned short* __restrict__ Wb,
                                                        const float* __restrict__ zb,
                                                        unsigned short* __restrict__ zA,
                                                        unsigned short* __restrict__ zB) {
  const int lane = threadIdx.x & 63;
  const int wv = threadIdx.x >> 6;     // = k (Chebyshev order)
  const int row0 = blockIdx.x * 4;
  const int col = lane & 15, quad = lane >> 4;
  const int ar = col >> 2, ab = col & 3;
  const unsigned short* xa = A + (size_t)(row0 + ar) * 256 + ab * 64 + quad * 8;
  const unsigned short* wb = Wb + (size_t)wv * 4 * 512 + lane * 8;   // [k][kc][t], KC=2, T=2
  unsigned short* zr = (wv < 2) ? (zA + (size_t)wv * VN * 128)
                                : (zB + (size_t)(wv - 2) * VN * 128);
  const short8 af0 = *reinterpret_cast<const short8*>(xa);
  const short8 af1 = *reinterpret_cast<const short8*>(xa + 32);
#pragma unroll
  for (int t = 0; t < 2; t++) {
    f32x4 acc = {0.f, 0.f, 0.f, 0.f};
    const short8 bf0 = *reinterpret_cast<const short8*>(wb + (size_t)(0 * 2 + t) * 512);
    const short8 bf1 = *reinterpret_cast<const short8*>(wb + (size_t)(1 * 2 + t) * 512);
    acc = __builtin_amdgcn_mfma_f32_16x16x32_bf16(af0, bf0, acc, 0, 0, 0);
    acc = __builtin_amdgcn_mfma_f32_16x16x32_bf16(af1, bf1, acc, 0, 0, 0);
    const int og = t * 16 + col;
    const float bs = zb[wv * 32 + og];
#pragma unroll
    for (int r = 0; r < 4; r++) {
      zr[(size_t)(row0 + quad) * 128 + r * 32 + og] = f2bf(acc[r] + bs);
    }
  }
}

// ---------- stats of SRC (already relu'd): rows (V)[b][o] stride 256, o in 0..63 ----------
__global__ __launch_bounds__(256) void stats_out_kernel(const unsigned short* __restrict__ SRC,
                                                        float* __restrict__ stats) {
  const int tid = threadIdx.x;  // tid = b*64 + o
  const int per = (VN + gridDim.x - 1) / gridDim.x;
  const int v0 = blockIdx.x * per;
  const int v1 = (v0 + per < VN) ? (v0 + per) : VN;
  float s = 0.f, s2 = 0.f;
  for (int v = v0; v < v1; v++) {
    float val = bf1(SRC[(size_t)v * 256 + tid]);
    s += val; s2 += val * val;
  }
  __shared__ float r1[256], r2[256];
  r1[tid] = s; r2[tid] = s2;
  __syncthreads();
  if (tid < 64) {  // sum the 4 batches for channel o = tid
    float a = r1[tid] + r1[tid + 64] + r1[tid + 128] + r1[tid + 192];
    float b = r2[tid] + r2[tid + 64] + r2[tid + 128] + r2[tid + 192];
    atomicAdd(&stats[tid], a);
    atomicAdd(&stats[64 + tid], b);
  }
}

// ---------- final: out[b,o,v] = relu(SRC[v,b,o] + xn[v,b,o]) ----------
__global__ __launch_bounds__(256) void final_kernel(const unsigned short* __restrict__ SRC,
                                                    const unsigned short* __restrict__ xn,
                                                    float* __restrict__ out) {
  const int lane = threadIdx.x & 63;
  const int grp = threadIdx.x >> 6;  // 0..3
  const int v = blockIdx.x * 64 + lane;
  if (v >= VN) return;
  for (int ob = grp; ob < 128; ob += 4) {  // ob = b*32 + o
    float val = bf1(SRC[(size_t)v * 128 + ob]) + bf1(xn[(size_t)v * 128 + ob]);
    val = fmaxf(val, 0.f);
    out[(size_t)ob * VN + v] = val;
  }
}

// ---------- workspace layout (~193 MB) ----------
static constexpr size_t align_up(size_t x) { return (x + 255) & ~(size_t)255; }
static constexpr size_t OFF_RP    = 0;
static constexpr size_t OFF_FILL  = align_up(OFF_RP + (size_t)(VN + 1) * 4);   // doubles as rowsum after CSR build
static constexpr size_t OFF_CHS   = align_up(OFF_FILL + (size_t)VN * 4);
static constexpr size_t OFF_CHO   = align_up(OFF_CHS + 256);
static constexpr size_t OFF_STATS = align_up(OFF_CHO + 256);
static constexpr size_t OFF_BIAS  = align_up(OFF_STATS + 1024);     // 64 (h0) + 128 (h1 zb) floats
static constexpr size_t OFF_WP    = align_up(OFF_BIAS + 1024);      // 32768 shorts = 64 KB
static constexpr size_t OFF_CS    = align_up(OFF_WP + 32768 * 2);
static constexpr size_t OFF_VS    = align_up(OFF_CS + (size_t)EN * 4);
static constexpr size_t OFF_XN    = align_up(OFF_VS + (size_t)EN * 4);
static constexpr size_t OFF_XL    = align_up(OFF_XN + (size_t)VN * 128 * 2);
static constexpr size_t OFF_A     = align_up(OFF_XL + (size_t)VN * 256 * 2);
static constexpr size_t OFF_B     = align_up(OFF_A + (size_t)VN * 256 * 2);
static constexpr size_t OFF_END   = OFF_B + (size_t)VN * 256 * 2;

extern "C" void kernel_launch(void* const* d_in, const int* in_sizes, int n_in,
                              void* d_out, int out_size, void* d_ws, size_t ws_size,
                              hipStream_t stream) {
  if (ws_size < OFF_END) return;  // diagnostic guard

  const float* x       = (const float*)d_in[0];
  const int*   rows    = (const int*)d_in[1];
  const int*   cols    = rows + EN;
  const float* lap     = (const float*)d_in[2];
  const float* in_bn_g = (const float*)d_in[3];
  const float* in_bn_b = (const float*)d_in[4];
  const float* in_w    = (const float*)d_in[5];
  const float* in_b    = (const float*)d_in[6];
  const float* h0_bn_g = (const float*)d_in[7];
  const float* h0_bn_b = (const float*)d_in[8];
  const float* h0_w    = (const float*)d_in[9];
  const float* h0_b    = (const float*)d_in[10];
  const float* h1_bn_g = (const float*)d_in[11];
  const float* h1_bn_b = (const float*)d_in[12];
  const float* h1_w    = (const float*)d_in[13];
  const float* h1_b    = (const float*)d_in[14];
  float* outp = (float*)d_out;

  char* ws = (char*)d_ws;
  int*   rp     = (int*)(ws + OFF_RP);
  int*   fill   = (int*)(ws + OFF_FILL);
  float* rowsum = (float*)(ws + OFF_FILL);   // overlays fill (dead after CSR build)
  int*   chS    = (int*)(ws + OFF_CHS);
  int*   chO    = (int*)(ws + OFF_CHO);
  float* stats  = (float*)(ws + OFF_STATS);
  float* biasF  = (float*)(ws + OFF_BIAS);   // [0..63] h0 folded bias; [64..191] h1 zb
  unsigned short* wbIn = (unsigned short*)(ws + OFF_WP);      // 8192 shorts
  unsigned short* wbH0 = wbIn + 8192;                         // 16384 shorts
  unsigned short* wbH1 = wbH0 + 16384;                        // 8192 shorts
  int*   cs     = (int*)(ws + OFF_CS);
  float* vs     = (float*)(ws + OFF_VS);
  unsigned short* xn = (unsigned short*)(ws + OFF_XN);
  unsigned short* XL = (unsigned short*)(ws + OFF_XL);
  unsigned short* A  = (unsigned short*)(ws + OFF_A);
  unsigned short* B  = (unsigned short*)(ws + OFF_B);
  const float* bnp = stats + 128;  // {sc[0..63], sh[0..63]}

  const int nChunks = (VN + 2047) / 2048;  // 49

  // ---- W pre-pack (layer "in" only; h0/h1 packs fold BN and launch after stats) ----
  pack_wb_kernel<<<32, 256, 0, stream>>>(in_w, wbIn, 32, 64, nullptr, 0);

  // ---- input BN stats + normalize/transpose ----
  hipMemsetAsync(stats, 0, 1024, stream);
  stats_x_kernel<<<1024, 256, 0, stream>>>(x, stats);
  finalize_stats_kernel<<<1, 64, 0, stream>>>(stats, in_bn_g, in_bn_b, 32);
  bn_transpose_kernel<<<1563, 128, 0, stream>>>(x, stats, xn);

  // ---- CSR build ----
  hipMemsetAsync(fill, 0, (size_t)VN * 4, stream);
  hist_kernel<<<2048, 256, 0, stream>>>(rows, fill);
  scan1_kernel<<<nChunks, 256, 0, stream>>>(fill, rp, chS);
  scan2_kernel<<<1, 64, 0, stream>>>(chS, chO, rp, nChunks);
  scan3_kernel<<<(VN + 255) / 256, 256, 0, stream>>>(rp, chO, fill);
  fill_kernel<<<2048, 256, 0, stream>>>(rows, cols, lap, fill, cs, vs);
  row_sum_kernel<<<(VN + 255) / 256, 256, 0, stream>>>(rp, vs, rowsum);  // fill now dead

  // ---- layer "in": Cin=32, Cout=64. x1/x2 compact (stride 128) in XL halves ----
  unsigned short* XLa = XL;                       // x1, VN*128 shorts
  unsigned short* XLb = XL + (size_t)VN * 128;    // x2
  spmm_kernel<2, 0, false, false><<<VN / 4, 256, 0, stream>>>(
      rp, cs, vs, xn, 128, nullptr, 0, nullptr, 0, XLa, 128, nullptr, nullptr);
  spmm_kernel<2, 1, false, false><<<VN / 4, 256, 0, stream>>>(
      rp, cs, vs, XLa, 128, xn, 128, nullptr, 0, XLb, 128, nullptr, nullptr);
  fused_cheb_kernel<32, 64, 128, 128, 128><<<VN / 4, 256, 0, stream>>>(
      rp, cs, vs, xn, XLa, XLb, A, wbIn, in_b);   // A := relu(out_in)
  hipMemsetAsync(stats, 0, 1024, stream);
  stats_out_kernel<<<256, 256, 0, stream>>>(A, stats);
  finalize_stats_kernel<<<1, 64, 0, stream>>>(stats, h0_bn_g, h0_bn_b, 64);

  // ---- h0 weight pack with BN fold: sc into k=0 weights, sh.W0 into bias ----
  pack_wb_kernel<<<64, 256, 0, stream>>>(h0_w, wbH0, 64, 64, bnp, 0x1);
  bias_fold_kernel<<<1, 128, 0, stream>>>(h0_w, h0_b, stats, biasF, 64, 64, 1);

  // ---- layer h0: Cin=64, Cout=64; A holds relu'd input, BN affine out of edge loops ----
  spmm_kernel<4, 0, true, false><<<VN / 4, 256, 0, stream>>>(
      rp, cs, vs, A, 256, nullptr, 0, nullptr, 0, XL, 256, bnp, rowsum);  // x1 = sc*L(relu) + rowsum*sh
  spmm_kernel<4, 1, false, true><<<VN / 4, 256, 0, stream>>>(
      rp, cs, vs, XL, 256, A, 256, nullptr, 0, B, 256, bnp, nullptr);     // x2 = 2 L x1 - affine(A)
  fused_cheb_kernel<64, 64, 256, 256, 256><<<VN / 4, 256, 0, stream>>>(
      rp, cs, vs, A, XL, B, A, wbH0, biasF);      // A := relu(out_h0), k=0 folded
  hipMemsetAsync(stats, 0, 1024, stream);
  stats_out_kernel<<<256, 256, 0, stream>>>(A, stats);
  finalize_stats_kernel<<<1, 64, 0, stream>>>(stats, h1_bn_g, h1_bn_b, 64);

  // ---- h1 weight pack with BN fold: sc into ALL k, per-k bias zb = sh.Wk (+b for k0) ----
  pack_wb_kernel<<<32, 256, 0, stream>>>(h1_w, wbH1, 64, 32, bnp, 0xF);
  bias_fold_kernel<<<1, 128, 0, stream>>>(h1_w, h1_b, stats, biasF + 64, 64, 32, 4);

  // ---- layer h1: Cin=64, Cout=32 via Clenshaw on 32-channel z_k ----
  {
    unsigned short* z0 = XL;
    unsigned short* z1 = XL + (size_t)VN * 128;
    unsigned short* z2 = B;
    unsigned short* z3 = B + (size_t)VN * 128;
    gemm_z_kernel<<<VN / 4, 256, 0, stream>>>(A, wbH1, biasF + 64, z0, z2);
    spmm_kernel<2, 2, false, false><<<VN / 4, 256, 0, stream>>>(
        rp, cs, vs, z3, 128, z2, 128, nullptr, 0, z2, 128, nullptr, nullptr);
    spmm_kernel<2, 3, false, false><<<VN / 4, 256, 0, stream>>>(
        rp, cs, vs, z2, 128, z1, 128, z3, 128, z1, 128, nullptr, nullptr);
    spmm_kernel<2, 4, false, false><<<VN / 4, 256, 0, stream>>>(
        rp, cs, vs, z1, 128, z0, 128, z2, 128, z0, 128, nullptr, nullptr);
    // ---- residual + relu + transpose to (B,32,V) ----
    final_kernel<<<1563, 256, 0, stream>>>(z0, xn, outp);
  }
}